// Round 4
// baseline (238.422 us; speedup 1.0000x reference)
//
#include <hip/hip_runtime.h>

#define NPTS 65536
#define WW 1024
#define HWCELLS 65536
#define EPSF 1e-5f
#define QPTS 16

typedef __attribute__((ext_vector_type(8))) short short8;
typedef __attribute__((ext_vector_type(4))) float f32x4;

// fast exact-gelu: Abramowitz-Stegun 7.1.25 erf approx (|err| <= 2.5e-5)
__device__ __forceinline__ float gelu_f(float x) {
    float z  = fabsf(x) * 0.70710678118654752f;
    float t  = __builtin_amdgcn_rcpf(fmaf(0.47047f, z, 1.0f));
    float p  = fmaf(fmaf(0.7478556f, t, -0.0958798f), t, 0.3480242f) * t;
    float e  = __builtin_amdgcn_exp2f(-1.4426950408889634f * z * z);
    float er = fmaf(-p, e, 1.0f);          // erf(|x|/sqrt2)
    float s  = copysignf(er, x);
    float hx = 0.5f * x;
    return fmaf(hx, s, hx);
}
__device__ __forceinline__ unsigned f2bf_rne(float x) {
    unsigned u = __float_as_uint(x);
    return (u + 0x7fffu + ((u >> 16) & 1u)) >> 16;
}
__device__ __forceinline__ unsigned pk2(float lo, float hi) {
    return f2bf_rne(lo) | (f2bf_rne(hi) << 16);
}
__device__ __forceinline__ float bflo(unsigned u) { return __uint_as_float(u << 16); }
__device__ __forceinline__ float bfhi(unsigned u) { return __uint_as_float(u & 0xffff0000u); }

// -1 fill of out (2M float4) + winner init (first 256 blocks)
__global__ void init_out_k(float4* __restrict__ out4, int* __restrict__ winner) {
    int i = blockIdx.x * 256 + threadIdx.x;
    out4[i] = make_float4(-1.f, -1.f, -1.f, -1.f);
    if (i < HWCELLS) winner[i] = -1;
}

__global__ void prep_k(const float* __restrict__ pc, const int* __restrict__ px,
                       const int* __restrict__ py,
                       const float* __restrict__ ng, const float* __restrict__ nb,
                       const float* __restrict__ nm, const float* __restrict__ nv,
                       float* __restrict__ xn8, int* __restrict__ winner) {
    int i = blockIdx.x * blockDim.x + threadIdx.x;
    if (i >= NPTS) return;
    float v[5];
#pragma unroll
    for (int c = 0; c < 5; ++c) {
        float s = ng[c] * rsqrtf(nv[c] + EPSF);
        float t = nb[c] - nm[c] * s;
        v[c] = pc[i * 5 + c] * s + t;
    }
    float4* dst = (float4*)&xn8[(size_t)i * 8];
    dst[0] = make_float4(v[0], v[1], v[2], v[3]);
    dst[1] = make_float4(v[4], 0.f, 0.f, 0.f);
    int cell = py[i] * WW + px[i];
    atomicMax(&winner[cell], i);
}

// per-256-cell-block winner counts
__global__ void cnt_k(const int* __restrict__ winner, int* __restrict__ blockcnt) {
    int cell = blockIdx.x * 256 + threadIdx.x;
    bool occ = winner[cell] >= 0;
    unsigned long long m = __ballot(occ);
    __shared__ int wcnt[4];
    int lane = threadIdx.x & 63, wv = threadIdx.x >> 6;
    if (lane == 0) wcnt[wv] = __popcll(m);
    __syncthreads();
    if (threadIdx.x == 0)
        blockcnt[blockIdx.x] = wcnt[0] + wcnt[1] + wcnt[2] + wcnt[3];
}

// exclusive scan of 256 block counts (1 block)
__global__ void scan_k(const int* __restrict__ blockcnt, int* __restrict__ blockoff,
                       int* __restrict__ count) {
    __shared__ int s[256];
    int t = threadIdx.x;
    int orig = blockcnt[t];
    s[t] = orig;
    __syncthreads();
    for (int off = 1; off < 256; off <<= 1) {
        int v = (t >= off) ? s[t - off] : 0;
        __syncthreads();
        s[t] += v;
        __syncthreads();
    }
    blockoff[t] = s[t] - orig;
    if (t == 255) *count = s[255];
}

// cell-ordered compaction: ids[slot] = winning point id, slot ascending in cell
__global__ void fill_k(const int* __restrict__ winner, const int* __restrict__ blockoff,
                       int* __restrict__ ids) {
    int cell = blockIdx.x * 256 + threadIdx.x;
    int win = winner[cell];
    bool occ = win >= 0;
    unsigned long long m = __ballot(occ);
    __shared__ int wcnt[4];
    int lane = threadIdx.x & 63, wv = threadIdx.x >> 6;
    if (lane == 0) wcnt[wv] = __popcll(m);
    __syncthreads();
    int woff = blockoff[blockIdx.x];
    for (int i = 0; i < wv; ++i) woff += wcnt[i];
    if (occ) {
        int lrank = __popcll(m & ((1ull << lane) - 1));
        ids[woff + lrank] = win;
    }
}

__global__ void pad_k(int* __restrict__ ids, const int* __restrict__ count) {
    int i = blockIdx.x * blockDim.x + threadIdx.x;
    int c = *count;
    if (i >= c && i < NPTS) ids[i] = ids[0];
}

__global__ void fold_k(const float* __restrict__ w2a,
                       const float* __restrict__ g2a, const float* __restrict__ b2a,
                       const float* __restrict__ m2a, const float* __restrict__ v2a,
                       const float* __restrict__ g2b, const float* __restrict__ b2b,
                       const float* __restrict__ m2b, const float* __restrict__ v2b,
                       const float* __restrict__ w2b,
                       const float* __restrict__ c1w, const float* __restrict__ c1b,
                       const float* __restrict__ fw, const float* __restrict__ fbias,
                       float* __restrict__ w2af8, float* __restrict__ b2o,
                       unsigned short* __restrict__ w2bB,
                       unsigned short* __restrict__ fwallB) {
    __shared__ float c1wS[640];
    __shared__ float c1bS[128];
    int d = threadIdx.x;  // 0..127
    for (int j = d; j < 640; j += 128) c1wS[j] = c1w[j];
    c1bS[d] = c1b[d];
    __syncthreads();

    float s2b = g2b[d] * rsqrtf(v2b[d] + EPSF);
    float t2b = b2b[d] - m2b[d] * s2b;
    float acc = 0.f;
#pragma unroll
    for (int c = 0; c < 5; ++c) {
        float s2a = g2a[c] * rsqrtf(v2a[c] + EPSF);
        float t2a = b2a[c] - m2a[c] * s2a;
        float wv = w2a[d * 5 + c];
        w2af8[d * 8 + c] = s2b * wv * s2a;
        acc += s2b * wv * t2a;
    }
    w2af8[d * 8 + 5] = 0.f; w2af8[d * 8 + 6] = 0.f; w2af8[d * 8 + 7] = 0.f;
    b2o[d] = acc + t2b;

#pragma unroll 8
    for (int i4 = 0; i4 < 32; ++i4) {
        float4 v = *(const float4*)&w2b[d * 128 + i4 * 4];
        unsigned short* dst = &w2bB[d * 128 + i4 * 4];
        dst[0] = (unsigned short)f2bf_rne(v.x);
        dst[1] = (unsigned short)f2bf_rne(v.y);
        dst[2] = (unsigned short)f2bf_rne(v.z);
        dst[3] = (unsigned short)f2bf_rne(v.w);
    }

    float f1[5] = {0.f, 0.f, 0.f, 0.f, 0.f};
    float fbv = fbias[d];
#pragma unroll 8
    for (int d4 = 0; d4 < 32; ++d4) {
        float4 fv = *(const float4*)&fw[d * 256 + d4 * 4];
        float4 fn = *(const float4*)&fw[d * 256 + 128 + d4 * 4];
        unsigned short* dst = &fwallB[d * 160 + d4 * 4];
        dst[0] = (unsigned short)f2bf_rne(fn.x);
        dst[1] = (unsigned short)f2bf_rne(fn.y);
        dst[2] = (unsigned short)f2bf_rne(fn.z);
        dst[3] = (unsigned short)f2bf_rne(fn.w);
        int dd = d4 * 4;
        fbv += fv.x * c1bS[dd] + fv.y * c1bS[dd+1] + fv.z * c1bS[dd+2] + fv.w * c1bS[dd+3];
#pragma unroll
        for (int c = 0; c < 5; ++c)
            f1[c] += fv.x * c1wS[dd*5 + c] + fv.y * c1wS[(dd+1)*5 + c]
                   + fv.z * c1wS[(dd+2)*5 + c] + fv.w * c1wS[(dd+3)*5 + c];
    }
#pragma unroll
    for (int c = 0; c < 5; ++c)
        fwallB[d * 160 + 128 + c] = (unsigned short)f2bf_rne(f1[c]);
    fwallB[d * 160 + 133] = (unsigned short)f2bf_rne(fbv);
    for (int j = 134; j < 160; ++j) fwallB[d * 160 + j] = 0;
}

// Y[n][din] bf16 = W2A' @ xn[n]  (no bias)
__global__ void y_k(const float* __restrict__ xn8, const float* __restrict__ w2af8,
                    unsigned short* __restrict__ Y) {
    __shared__ float wS[1024];
    int t = threadIdx.x;
    for (int j = t; j < 1024; j += 256) wS[j] = w2af8[j];
    __syncthreads();
    int n = blockIdx.x * 256 + t;
    const float4 xa = *(const float4*)&xn8[(size_t)n * 8];
    const float x4 = xn8[(size_t)n * 8 + 4];
    unsigned* Yo = (unsigned*)(Y + (size_t)n * 128);
#pragma unroll
    for (int blk = 0; blk < 16; ++blk) {
        unsigned p[4];
#pragma unroll
        for (int q = 0; q < 4; ++q) {
            int dd = blk * 8 + q * 2;
            const float* wr = &wS[dd * 8];
            float a = wr[0]*xa.x + wr[1]*xa.y + wr[2]*xa.z + wr[3]*xa.w + wr[4]*x4;
            const float* wr2 = &wS[(dd + 1) * 8];
            float b = wr2[0]*xa.x + wr2[1]*xa.y + wr2[2]*xa.z + wr2[3]*xa.w + wr2[4]*x4;
            p[q] = pk2(a, b);
        }
        uint4 u; u.x = p[0]; u.y = p[1]; u.z = p[2]; u.w = p[3];
        *(uint4*)&Yo[blk * 4] = u;
    }
}

// fused MFMA main over cell-ordered winners: 16 pts/block, 256 thr (4 waves)
__launch_bounds__(256, 8)
__global__ void main_k(const int* __restrict__ ids, const int* __restrict__ countp,
                       const int* __restrict__ nbrs,
                       const float* __restrict__ xn8,
                       const int* __restrict__ px, const int* __restrict__ py,
                       const unsigned short* __restrict__ Y,
                       const float* __restrict__ b2,
                       const unsigned short* __restrict__ w2bB,
                       const unsigned short* __restrict__ fwallB,
                       float* __restrict__ outp) {
    const int n0 = blockIdx.x * QPTS;
    if (n0 >= *countp) return;

    __shared__ char  lds[8192];    // G double buffer (2x4096); M (5120) overlays
    __shared__ int   idS[QPTS];
    __shared__ int   nbS[QPTS * 16];
    __shared__ float xnS[QPTS][8];
    __shared__ int   cellS[QPTS];

    const int t = threadIdx.x;
    const int w = t >> 6;
    const int l = t & 63;
    const int l15 = l & 15;
    const int lg  = l >> 4;

    if (t < QPTS) idS[t] = ids[n0 + t];
    __syncthreads();

    nbS[t] = nbrs[idS[t >> 4] * 16 + (t & 15)];
    if (t < QPTS) {
        int id = idS[t];
        float4 a = *(const float4*)&xn8[(size_t)id * 8];
        float b = xn8[(size_t)id * 8 + 4];
        xnS[t][0] = a.x; xnS[t][1] = a.y; xnS[t][2] = a.z; xnS[t][3] = a.w;
        xnS[t][4] = b;
        cellS[t] = py[id] * WW + px[id];
    }

    // A fragments: w2b rows [w*32, w*32+32), all K=128
    short8 afrag[2][4];
#pragma unroll
    for (int rt = 0; rt < 2; ++rt)
#pragma unroll
        for (int ks = 0; ks < 4; ++ks) {
            int row = w * 32 + rt * 16 + l15;
            int k0 = ks * 32 + lg * 8;
            afrag[rt][ks] = *(const short8*)(w2bB + row * 128 + k0);
        }

    // g-producer role: dins dinblk*4..+3, pts ptblk*2..+1
    const int dinblk = t & 31;
    const int ptblk  = t >> 5;   // 0..7
    const uint2* __restrict__ Y2 = (const uint2*)Y;   // 32 uint2 per row
    const float4 b2q = *(const float4*)&b2[dinblk * 4];
    float c0a[2][4];
#pragma unroll
    for (int i = 0; i < 2; ++i) {
        int id = idS[ptblk * 2 + i];
        uint2 yp = Y2[id * 32 + dinblk];
        c0a[i][0] = b2q.x - bflo(yp.x);
        c0a[i][1] = b2q.y - bfhi(yp.x);
        c0a[i][2] = b2q.z - bflo(yp.y);
        c0a[i][3] = b2q.w - bfhi(yp.y);
    }
    __syncthreads();  // nbS ready

    uint2 ycur[2], ynxt[2];
#pragma unroll
    for (int i = 0; i < 2; ++i) {
        int nb = nbS[(ptblk * 2 + i) * 16 + 1];
        ycur[i] = Y2[nb * 32 + dinblk];
    }

    const f32x4 zero4 = {0.f, 0.f, 0.f, 0.f};
    f32x4 mmax[2];
#pragma unroll
    for (int rt = 0; rt < 2; ++rt)
#pragma unroll
        for (int j = 0; j < 4; ++j) mmax[rt][j] = -1e30f;

    for (int kk = 0; kk < 15; ++kk) {
        if (kk < 14) {
#pragma unroll
            for (int i = 0; i < 2; ++i) {
                int nb = nbS[(ptblk * 2 + i) * 16 + kk + 2];
                ynxt[i] = Y2[nb * 32 + dinblk];
            }
        }
        {   // gelu -> G[kk&1]
            char* Gb = lds + (kk & 1) * 4096;
#pragma unroll
            for (int i = 0; i < 2; ++i) {
                int pt = ptblk * 2 + i;
                float g0 = gelu_f(bflo(ycur[i].x) + c0a[i][0]);
                float g1 = gelu_f(bfhi(ycur[i].x) + c0a[i][1]);
                float g2 = gelu_f(bflo(ycur[i].y) + c0a[i][2]);
                float g3 = gelu_f(bfhi(ycur[i].y) + c0a[i][3]);
                uint2 pr; pr.x = pk2(g0, g1); pr.y = pk2(g2, g3);
                *(uint2*)(Gb + pt * 256 + ((dinblk * 8) ^ (pt << 4))) = pr;
            }
        }
        __syncthreads();
        {   // MFMA on G[kk&1]
            const char* Gr = lds + (kk & 1) * 4096;
            f32x4 acc[2];
#pragma unroll
            for (int ks = 0; ks < 4; ++ks) {
                int kb = (ks * 32 + lg * 8) * 2;
                short8 bfrag = *(const short8*)(Gr + l15 * 256 + (kb ^ (l15 << 4)));
#pragma unroll
                for (int rt = 0; rt < 2; ++rt)
                    acc[rt] = __builtin_amdgcn_mfma_f32_16x16x32_bf16(
                        afrag[rt][ks], bfrag, ks == 0 ? zero4 : acc[rt], 0, 0, 0);
            }
#pragma unroll
            for (int rt = 0; rt < 2; ++rt)
#pragma unroll
                for (int j = 0; j < 4; ++j)
                    mmax[rt][j] = fmaxf(mmax[rt][j], acc[rt][j]);
        }
        if (kk < 14) {
#pragma unroll
            for (int i = 0; i < 2; ++i) ycur[i] = ynxt[i];
        }
    }

    __syncthreads();  // all MFMA reads of G done before M overlay

    // running max -> M as B-operand [pt][k=dout] bf16 (k<128 swizzled), + xn tail
    {
        char* Mb = lds;
        int sw = l15 << 4;
#pragma unroll
        for (int rt = 0; rt < 2; ++rt) {
            int dout = w * 32 + rt * 16 + lg * 4;
            unsigned lo = pk2(mmax[rt][0], mmax[rt][1]);
            unsigned hi = pk2(mmax[rt][2], mmax[rt][3]);
            *(unsigned*)(Mb + l15 * 320 + ((dout * 2) ^ sw)) = lo;
            *(unsigned*)(Mb + l15 * 320 + (((dout + 2) * 2) ^ sw)) = hi;
        }
        if (t < QPTS) {
            unsigned v0 = pk2(xnS[t][0], xnS[t][1]);
            unsigned v1 = pk2(xnS[t][2], xnS[t][3]);
            unsigned v2 = pk2(xnS[t][4], 1.0f);
            uint4 a; a.x = v0; a.y = v1; a.z = v2; a.w = 0u;
            uint4 z; z.x = 0u; z.y = 0u; z.z = 0u; z.w = 0u;
            *(uint4*)(Mb + t * 320 + 256) = a;
            *(uint4*)(Mb + t * 320 + 272) = z;
            *(uint4*)(Mb + t * 320 + 288) = z;
            *(uint4*)(Mb + t * 320 + 304) = z;
        }
    }
    __syncthreads();

    // final GEMM: feats[e][pt] = fwallB(128x160) @ M(160xQPTS)
    f32x4 facc[2];
    const char* Mr = lds;
#pragma unroll
    for (int ks = 0; ks < 5; ++ks) {
        short8 af[2];
#pragma unroll
        for (int rt = 0; rt < 2; ++rt) {
            int row = w * 32 + rt * 16 + l15;
            af[rt] = *(const short8*)(fwallB + row * 160 + ks * 32 + lg * 8);
        }
        int kb = (ks * 32 + lg * 8) * 2;
        int kbs = (kb < 256) ? (kb ^ (l15 << 4)) : kb;
        short8 bfr = *(const short8*)(Mr + l15 * 320 + kbs);
#pragma unroll
        for (int rt = 0; rt < 2; ++rt)
            facc[rt] = __builtin_amdgcn_mfma_f32_16x16x32_bf16(
                af[rt], bfr, ks == 0 ? zero4 : facc[rt], 0, 0, 0);
    }

    // direct scatter: cells ascending within block -> near-coalesced lines
    const int cell = cellS[l15];
#pragma unroll
    for (int rt = 0; rt < 2; ++rt) {
        int e0 = w * 32 + rt * 16 + lg * 4;
#pragma unroll
        for (int j = 0; j < 4; ++j)
            outp[(size_t)(e0 + j) * HWCELLS + cell] = facc[rt][j];
    }
}

extern "C" void kernel_launch(void* const* d_in, const int* in_sizes, int n_in,
                              void* d_out, int out_size, void* d_ws, size_t ws_size,
                              hipStream_t stream) {
    const float* pc        = (const float*)d_in[0];
    const int*   neighbors = (const int*)d_in[1];
    const int*   px        = (const int*)d_in[2];
    const int*   py        = (const int*)d_in[3];
    const float* norm_g    = (const float*)d_in[4];
    const float* norm_b    = (const float*)d_in[5];
    const float* norm_m    = (const float*)d_in[6];
    const float* norm_v    = (const float*)d_in[7];
    const float* conv1_w   = (const float*)d_in[8];
    const float* conv1_b   = (const float*)d_in[9];
    const float* bn2a_g    = (const float*)d_in[10];
    const float* bn2a_b    = (const float*)d_in[11];
    const float* bn2a_m    = (const float*)d_in[12];
    const float* bn2a_v    = (const float*)d_in[13];
    const float* w2a       = (const float*)d_in[14];
    const float* bn2b_g    = (const float*)d_in[15];
    const float* bn2b_b    = (const float*)d_in[16];
    const float* bn2b_m    = (const float*)d_in[17];
    const float* bn2b_v    = (const float*)d_in[18];
    const float* w2b       = (const float*)d_in[19];
    const float* final_w   = (const float*)d_in[20];
    const float* final_b   = (const float*)d_in[21];
    float* out = (float*)d_out;

    char* ws = (char*)d_ws;
    float*          xn8      = (float*)(ws);                      // 2,097,152 B
    int*            winner   = (int*)(ws + 2097152);              //   262,144 B
    int*            ids      = (int*)(ws + 2359296);              //   262,144 B
    int*            count    = (int*)(ws + 2621440);              //       256 B
    int*            blockcnt = (int*)(ws + 2621696);              //     1,024 B
    int*            blockoff = (int*)(ws + 2622720);              //     1,024 B
    float*          w2af8    = (float*)(ws + 2623744);            //     4,096 B
    float*          b2       = (float*)(ws + 2627840);            //       512 B
    unsigned short* w2bB     = (unsigned short*)(ws + 2628352);   //    32,768 B
    unsigned short* fwallB   = (unsigned short*)(ws + 2661120);   //    40,960 B
    unsigned short* Y        = (unsigned short*)(ws + 2702080);   // 16,777,216 B

    init_out_k<<<8192, 256, 0, stream>>>((float4*)out, winner);
    prep_k<<<256, 256, 0, stream>>>(pc, px, py, norm_g, norm_b, norm_m, norm_v, xn8, winner);
    fold_k<<<1, 128, 0, stream>>>(w2a, bn2a_g, bn2a_b, bn2a_m, bn2a_v,
                                  bn2b_g, bn2b_b, bn2b_m, bn2b_v, w2b,
                                  conv1_w, conv1_b, final_w, final_b,
                                  w2af8, b2, w2bB, fwallB);
    y_k<<<256, 256, 0, stream>>>(xn8, w2af8, Y);
    cnt_k<<<256, 256, 0, stream>>>(winner, blockcnt);
    scan_k<<<1, 256, 0, stream>>>(blockcnt, blockoff, count);
    fill_k<<<256, 256, 0, stream>>>(winner, blockoff, ids);
    pad_k<<<256, 256, 0, stream>>>(ids, count);
    main_k<<<4096, 256, 0, stream>>>(ids, count, neighbors, xn8, px, py,
                                     Y, b2, w2bB, fwallB, out);
}

// Round 5
// 133.252 us; speedup vs baseline: 1.7893x; 1.7893x over previous
//
#include <hip/hip_runtime.h>

#define NPTS 65536
#define WW 1024
#define HWCELLS 65536
#define EPSF 1e-5f
#define QPTS 16

typedef __attribute__((ext_vector_type(8))) short short8;
typedef __attribute__((ext_vector_type(4))) float f32x4;

// fast exact-gelu: Abramowitz-Stegun 7.1.25 erf approx (|err| <= 2.5e-5)
__device__ __forceinline__ float gelu_f(float x) {
    float z  = fabsf(x) * 0.70710678118654752f;
    float t  = __builtin_amdgcn_rcpf(fmaf(0.47047f, z, 1.0f));
    float p  = fmaf(fmaf(0.7478556f, t, -0.0958798f), t, 0.3480242f) * t;
    float e  = __builtin_amdgcn_exp2f(-1.4426950408889634f * z * z);
    float er = fmaf(-p, e, 1.0f);          // erf(|x|/sqrt2)
    float s  = copysignf(er, x);
    float hx = 0.5f * x;
    return fmaf(hx, s, hx);
}
__device__ __forceinline__ unsigned f2bf_rne(float x) {
    unsigned u = __float_as_uint(x);
    return (u + 0x7fffu + ((u >> 16) & 1u)) >> 16;
}
__device__ __forceinline__ unsigned pk2(float lo, float hi) {
    return f2bf_rne(lo) | (f2bf_rne(hi) << 16);
}

// -1 fill of out (2M float4) + winner init (first 256 blocks)
__global__ void init_out_k(float4* __restrict__ out4, int* __restrict__ winner) {
    int i = blockIdx.x * 256 + threadIdx.x;
    out4[i] = make_float4(-1.f, -1.f, -1.f, -1.f);
    if (i < HWCELLS) winner[i] = -1;
}

// pure repack: pc -> xn4 (c0..c3) + xn1 (c4); winner atomicMax
__global__ void prep_k(const float* __restrict__ pc, const int* __restrict__ px,
                       const int* __restrict__ py,
                       float4* __restrict__ xn4, float* __restrict__ xn1,
                       int* __restrict__ winner) {
    int i = blockIdx.x * blockDim.x + threadIdx.x;
    if (i >= NPTS) return;
    const float* p = &pc[(size_t)i * 5];
    xn4[i] = make_float4(p[0], p[1], p[2], p[3]);
    xn1[i] = p[4];
    int cell = py[i] * WW + px[i];
    atomicMax(&winner[cell], i);
}

// per-256-cell-block winner counts
__global__ void cnt_k(const int* __restrict__ winner, int* __restrict__ blockcnt) {
    int cell = blockIdx.x * 256 + threadIdx.x;
    bool occ = winner[cell] >= 0;
    unsigned long long m = __ballot(occ);
    __shared__ int wcnt[4];
    int lane = threadIdx.x & 63, wv = threadIdx.x >> 6;
    if (lane == 0) wcnt[wv] = __popcll(m);
    __syncthreads();
    if (threadIdx.x == 0)
        blockcnt[blockIdx.x] = wcnt[0] + wcnt[1] + wcnt[2] + wcnt[3];
}

// exclusive scan of 256 block counts (1 block)
__global__ void scan_k(const int* __restrict__ blockcnt, int* __restrict__ blockoff,
                       int* __restrict__ count) {
    __shared__ int s[256];
    int t = threadIdx.x;
    int orig = blockcnt[t];
    s[t] = orig;
    __syncthreads();
    for (int off = 1; off < 256; off <<= 1) {
        int v = (t >= off) ? s[t - off] : 0;
        __syncthreads();
        s[t] += v;
        __syncthreads();
    }
    blockoff[t] = s[t] - orig;
    if (t == 255) *count = s[255];
}

// cell-ordered compaction: ids[slot] = winning point id, slot ascending in cell
__global__ void fill_k(const int* __restrict__ winner, const int* __restrict__ blockoff,
                       int* __restrict__ ids) {
    int cell = blockIdx.x * 256 + threadIdx.x;
    int win = winner[cell];
    bool occ = win >= 0;
    unsigned long long m = __ballot(occ);
    __shared__ int wcnt[4];
    int lane = threadIdx.x & 63, wv = threadIdx.x >> 6;
    if (lane == 0) wcnt[wv] = __popcll(m);
    __syncthreads();
    int woff = blockoff[blockIdx.x];
    for (int i = 0; i < wv; ++i) woff += wcnt[i];
    if (occ) {
        int lrank = __popcll(m & ((1ull << lane) - 1));
        ids[woff + lrank] = win;
    }
}

__global__ void pad_k(int* __restrict__ ids, const int* __restrict__ count) {
    int i = blockIdx.x * blockDim.x + threadIdx.x;
    int c = *count;
    if (i >= c && i < NPTS) ids[i] = ids[0];
}

// fold ALL BN affines (incl. input norm) into compact weights, raw-pc basis
__global__ void fold_k(const float* __restrict__ ng, const float* __restrict__ nbta,
                       const float* __restrict__ nm, const float* __restrict__ nv,
                       const float* __restrict__ w2a,
                       const float* __restrict__ g2a, const float* __restrict__ b2a,
                       const float* __restrict__ m2a, const float* __restrict__ v2a,
                       const float* __restrict__ g2b, const float* __restrict__ b2b,
                       const float* __restrict__ m2b, const float* __restrict__ v2b,
                       const float* __restrict__ w2b,
                       const float* __restrict__ c1w, const float* __restrict__ c1b,
                       const float* __restrict__ fw, const float* __restrict__ fbias,
                       float* __restrict__ w2af8, float* __restrict__ b2o,
                       unsigned short* __restrict__ w2bB,
                       unsigned short* __restrict__ fwallB) {
    __shared__ float c1wS[640];
    __shared__ float c1adjS[128];
    int d = threadIdx.x;  // 0..127

    float s_n[5], t_n[5];
#pragma unroll
    for (int c = 0; c < 5; ++c) {
        s_n[c] = ng[c] * rsqrtf(nv[c] + EPSF);
        t_n[c] = nbta[c] - nm[c] * s_n[c];
    }
    for (int j = d; j < 640; j += 128) c1wS[j] = c1w[j];
    __syncthreads();
    {   // c1adj[dd] = c1b[dd] + sum_c c1w[dd][c]*t_n[c]
        float a = c1b[d];
#pragma unroll
        for (int c = 0; c < 5; ++c) a += c1wS[d * 5 + c] * t_n[c];
        c1adjS[d] = a;
    }
    __syncthreads();

    float s2b = g2b[d] * rsqrtf(v2b[d] + EPSF);
    float t2b = b2b[d] - m2b[d] * s2b;
    float acc = 0.f;
#pragma unroll
    for (int c = 0; c < 5; ++c) {
        float s2a = g2a[c] * rsqrtf(v2a[c] + EPSF);
        float t2a = b2a[c] - m2a[c] * s2a;
        float wv = w2a[d * 5 + c];
        w2af8[d * 8 + c] = s2b * wv * s2a * s_n[c];   // raw-pc-diff basis
        acc += s2b * wv * t2a;
    }
    w2af8[d * 8 + 5] = 0.f; w2af8[d * 8 + 6] = 0.f; w2af8[d * 8 + 7] = 0.f;
    b2o[d] = acc + t2b;

#pragma unroll 8
    for (int i4 = 0; i4 < 32; ++i4) {
        float4 v = *(const float4*)&w2b[d * 128 + i4 * 4];
        unsigned short* dst = &w2bB[d * 128 + i4 * 4];
        dst[0] = (unsigned short)f2bf_rne(v.x);
        dst[1] = (unsigned short)f2bf_rne(v.y);
        dst[2] = (unsigned short)f2bf_rne(v.z);
        dst[3] = (unsigned short)f2bf_rne(v.w);
    }

    float f1[5] = {0.f, 0.f, 0.f, 0.f, 0.f};
    float fbv = fbias[d];
#pragma unroll 8
    for (int d4 = 0; d4 < 32; ++d4) {
        float4 fv = *(const float4*)&fw[d * 256 + d4 * 4];
        float4 fn = *(const float4*)&fw[d * 256 + 128 + d4 * 4];
        unsigned short* dst = &fwallB[d * 160 + d4 * 4];
        dst[0] = (unsigned short)f2bf_rne(fn.x);
        dst[1] = (unsigned short)f2bf_rne(fn.y);
        dst[2] = (unsigned short)f2bf_rne(fn.z);
        dst[3] = (unsigned short)f2bf_rne(fn.w);
        int dd = d4 * 4;
        fbv += fv.x * c1adjS[dd] + fv.y * c1adjS[dd+1] + fv.z * c1adjS[dd+2] + fv.w * c1adjS[dd+3];
#pragma unroll
        for (int c = 0; c < 5; ++c)
            f1[c] += fv.x * c1wS[dd*5 + c] + fv.y * c1wS[(dd+1)*5 + c]
                   + fv.z * c1wS[(dd+2)*5 + c] + fv.w * c1wS[(dd+3)*5 + c];
    }
#pragma unroll
    for (int c = 0; c < 5; ++c)
        fwallB[d * 160 + 128 + c] = (unsigned short)f2bf_rne(f1[c] * s_n[c]);
    fwallB[d * 160 + 133] = (unsigned short)f2bf_rne(fbv);
    for (int j = 134; j < 160; ++j) fwallB[d * 160 + j] = 0;
}

// fused MFMA main over cell-ordered winners: 16 pts/block, 256 thr (4 waves)
// gathers 20B raw xn per neighbor (L2-resident), recomputes 5->128 in-reg
__launch_bounds__(256, 4)
__global__ void main_k(const int* __restrict__ ids, const int* __restrict__ countp,
                       const int* __restrict__ nbrs,
                       const float4* __restrict__ xn4, const float* __restrict__ xn1,
                       const int* __restrict__ px, const int* __restrict__ py,
                       const float* __restrict__ b2,
                       const float* __restrict__ w2af8,
                       const unsigned short* __restrict__ w2bB,
                       const unsigned short* __restrict__ fwallB,
                       float* __restrict__ outp) {
    const int n0 = blockIdx.x * QPTS;
    if (n0 >= *countp) return;

    __shared__ char  lds[8192];    // G double buffer (2x4096); M (5120) overlays
    __shared__ int   idS[QPTS];
    __shared__ int   nbS[QPTS * 16];
    __shared__ float xnS[QPTS][8];
    __shared__ int   cellS[QPTS];

    const int t = threadIdx.x;
    const int w = t >> 6;
    const int l = t & 63;
    const int l15 = l & 15;
    const int lg  = l >> 4;

    if (t < QPTS) idS[t] = ids[n0 + t];
    __syncthreads();

    nbS[t] = nbrs[idS[t >> 4] * 16 + (t & 15)];
    if (t < QPTS) {
        int id = idS[t];
        float4 a = xn4[id];
        xnS[t][0] = a.x; xnS[t][1] = a.y; xnS[t][2] = a.z; xnS[t][3] = a.w;
        xnS[t][4] = xn1[id];
        cellS[t] = py[id] * WW + px[id];
    }

    // A fragments: w2b rows [w*32, w*32+32), all K=128
    short8 afrag[2][4];
#pragma unroll
    for (int rt = 0; rt < 2; ++rt)
#pragma unroll
        for (int ks = 0; ks < 4; ++ks) {
            int row = w * 32 + rt * 16 + l15;
            int k0 = ks * 32 + lg * 8;
            afrag[rt][ks] = *(const short8*)(w2bB + row * 128 + k0);
        }

    // g-producer role: dins dinblk*4..+3, pts ptblk*2..+1
    const int dinblk = t & 31;
    const int ptblk  = t >> 5;   // 0..7

    float wv[4][5];
    float b2r[4];
    {
        float4 b2q = *(const float4*)&b2[dinblk * 4];
        b2r[0] = b2q.x; b2r[1] = b2q.y; b2r[2] = b2q.z; b2r[3] = b2q.w;
#pragma unroll
        for (int q = 0; q < 4; ++q) {
            float4 a = *(const float4*)&w2af8[(dinblk * 4 + q) * 8];
            wv[q][0] = a.x; wv[q][1] = a.y; wv[q][2] = a.z; wv[q][3] = a.w;
            wv[q][4] = w2af8[(dinblk * 4 + q) * 8 + 4];
        }
    }

    // self xn (raw) in regs
    float4 s4[2]; float s1[2];
#pragma unroll
    for (int i = 0; i < 2; ++i) {
        int id = idS[ptblk * 2 + i];
        s4[i] = xn4[id];
        s1[i] = xn1[id];
    }
    __syncthreads();  // nbS ready

    float4 c4[2]; float c1v[2];
    float4 n4[2]; float n1v[2];
#pragma unroll
    for (int i = 0; i < 2; ++i) {
        int nb = nbS[(ptblk * 2 + i) * 16 + 1];
        c4[i] = xn4[nb];
        c1v[i] = xn1[nb];
    }

    const f32x4 zero4 = {0.f, 0.f, 0.f, 0.f};
    f32x4 mmax[2];
#pragma unroll
    for (int rt = 0; rt < 2; ++rt)
#pragma unroll
        for (int j = 0; j < 4; ++j) mmax[rt][j] = -1e30f;

    for (int kk = 0; kk < 15; ++kk) {
        if (kk < 14) {
#pragma unroll
            for (int i = 0; i < 2; ++i) {
                int nb = nbS[(ptblk * 2 + i) * 16 + kk + 2];
                n4[i] = xn4[nb];
                n1v[i] = xn1[nb];
            }
        }
        {   // dx -> 5->128 matvec -> gelu -> G[kk&1]
            char* Gb = lds + (kk & 1) * 4096;
#pragma unroll
            for (int i = 0; i < 2; ++i) {
                int pt = ptblk * 2 + i;
                float dx0 = c4[i].x - s4[i].x;
                float dx1 = c4[i].y - s4[i].y;
                float dx2 = c4[i].z - s4[i].z;
                float dx3 = c4[i].w - s4[i].w;
                float dx4 = c1v[i] - s1[i];
                float g[4];
#pragma unroll
                for (int q = 0; q < 4; ++q) {
                    float s = b2r[q];
                    s = fmaf(wv[q][0], dx0, s);
                    s = fmaf(wv[q][1], dx1, s);
                    s = fmaf(wv[q][2], dx2, s);
                    s = fmaf(wv[q][3], dx3, s);
                    s = fmaf(wv[q][4], dx4, s);
                    g[q] = gelu_f(s);
                }
                uint2 pr; pr.x = pk2(g[0], g[1]); pr.y = pk2(g[2], g[3]);
                *(uint2*)(Gb + pt * 256 + ((dinblk * 8) ^ (pt << 4))) = pr;
            }
        }
        __syncthreads();
        {   // MFMA on G[kk&1]
            const char* Gr = lds + (kk & 1) * 4096;
            f32x4 acc[2];
#pragma unroll
            for (int ks = 0; ks < 4; ++ks) {
                int kb = (ks * 32 + lg * 8) * 2;
                short8 bfrag = *(const short8*)(Gr + l15 * 256 + (kb ^ (l15 << 4)));
#pragma unroll
                for (int rt = 0; rt < 2; ++rt)
                    acc[rt] = __builtin_amdgcn_mfma_f32_16x16x32_bf16(
                        afrag[rt][ks], bfrag, ks == 0 ? zero4 : acc[rt], 0, 0, 0);
            }
#pragma unroll
            for (int rt = 0; rt < 2; ++rt)
#pragma unroll
                for (int j = 0; j < 4; ++j)
                    mmax[rt][j] = fmaxf(mmax[rt][j], acc[rt][j]);
        }
        if (kk < 14) {
#pragma unroll
            for (int i = 0; i < 2; ++i) { c4[i] = n4[i]; c1v[i] = n1v[i]; }
        }
    }

    __syncthreads();  // all MFMA reads of G done before M overlay

    // running max -> M as B-operand [pt][k=dout] bf16 (k<128 swizzled), + xn tail
    {
        char* Mb = lds;
        int sw = l15 << 4;
#pragma unroll
        for (int rt = 0; rt < 2; ++rt) {
            int dout = w * 32 + rt * 16 + lg * 4;
            unsigned lo = pk2(mmax[rt][0], mmax[rt][1]);
            unsigned hi = pk2(mmax[rt][2], mmax[rt][3]);
            *(unsigned*)(Mb + l15 * 320 + ((dout * 2) ^ sw)) = lo;
            *(unsigned*)(Mb + l15 * 320 + (((dout + 2) * 2) ^ sw)) = hi;
        }
        if (t < QPTS) {
            unsigned v0 = pk2(xnS[t][0], xnS[t][1]);
            unsigned v1 = pk2(xnS[t][2], xnS[t][3]);
            unsigned v2 = pk2(xnS[t][4], 1.0f);
            uint4 a; a.x = v0; a.y = v1; a.z = v2; a.w = 0u;
            uint4 z; z.x = 0u; z.y = 0u; z.z = 0u; z.w = 0u;
            *(uint4*)(Mb + t * 320 + 256) = a;
            *(uint4*)(Mb + t * 320 + 272) = z;
            *(uint4*)(Mb + t * 320 + 288) = z;
            *(uint4*)(Mb + t * 320 + 304) = z;
        }
    }
    __syncthreads();

    // final GEMM: feats[e][pt] = fwallB(128x160) @ M(160xQPTS)
    f32x4 facc[2];
    const char* Mr = lds;
#pragma unroll
    for (int ks = 0; ks < 5; ++ks) {
        short8 af[2];
#pragma unroll
        for (int rt = 0; rt < 2; ++rt) {
            int row = w * 32 + rt * 16 + l15;
            af[rt] = *(const short8*)(fwallB + row * 160 + ks * 32 + lg * 8);
        }
        int kb = (ks * 32 + lg * 8) * 2;
        int kbs = (kb < 256) ? (kb ^ (l15 << 4)) : kb;
        short8 bfr = *(const short8*)(Mr + l15 * 320 + kbs);
#pragma unroll
        for (int rt = 0; rt < 2; ++rt)
            facc[rt] = __builtin_amdgcn_mfma_f32_16x16x32_bf16(
                af[rt], bfr, ks == 0 ? zero4 : facc[rt], 0, 0, 0);
    }

    // direct scatter: cells ascending within block -> near-coalesced lines
    const int cell = cellS[l15];
#pragma unroll
    for (int rt = 0; rt < 2; ++rt) {
        int e0 = w * 32 + rt * 16 + lg * 4;
#pragma unroll
        for (int j = 0; j < 4; ++j)
            outp[(size_t)(e0 + j) * HWCELLS + cell] = facc[rt][j];
    }
}

extern "C" void kernel_launch(void* const* d_in, const int* in_sizes, int n_in,
                              void* d_out, int out_size, void* d_ws, size_t ws_size,
                              hipStream_t stream) {
    const float* pc        = (const float*)d_in[0];
    const int*   neighbors = (const int*)d_in[1];
    const int*   px        = (const int*)d_in[2];
    const int*   py        = (const int*)d_in[3];
    const float* norm_g    = (const float*)d_in[4];
    const float* norm_b    = (const float*)d_in[5];
    const float* norm_m    = (const float*)d_in[6];
    const float* norm_v    = (const float*)d_in[7];
    const float* conv1_w   = (const float*)d_in[8];
    const float* conv1_b   = (const float*)d_in[9];
    const float* bn2a_g    = (const float*)d_in[10];
    const float* bn2a_b    = (const float*)d_in[11];
    const float* bn2a_m    = (const float*)d_in[12];
    const float* bn2a_v    = (const float*)d_in[13];
    const float* w2a       = (const float*)d_in[14];
    const float* bn2b_g    = (const float*)d_in[15];
    const float* bn2b_b    = (const float*)d_in[16];
    const float* bn2b_m    = (const float*)d_in[17];
    const float* bn2b_v    = (const float*)d_in[18];
    const float* w2b       = (const float*)d_in[19];
    const float* final_w   = (const float*)d_in[20];
    const float* final_b   = (const float*)d_in[21];
    float* out = (float*)d_out;

    char* ws = (char*)d_ws;
    float4*         xn4      = (float4*)(ws);                     // 1,048,576 B
    float*          xn1      = (float*)(ws + 1048576);            //   262,144 B
    int*            winner   = (int*)(ws + 1310720);              //   262,144 B
    int*            ids      = (int*)(ws + 1572864);              //   262,144 B
    int*            count    = (int*)(ws + 1835008);              //       256 B
    int*            blockcnt = (int*)(ws + 1835264);              //     1,024 B
    int*            blockoff = (int*)(ws + 1836288);              //     1,024 B
    float*          w2af8    = (float*)(ws + 1837312);            //     4,096 B
    float*          b2       = (float*)(ws + 1841408);            //       512 B
    unsigned short* w2bB     = (unsigned short*)(ws + 1841920);   //    32,768 B
    unsigned short* fwallB   = (unsigned short*)(ws + 1874688);   //    40,960 B

    init_out_k<<<8192, 256, 0, stream>>>((float4*)out, winner);
    prep_k<<<256, 256, 0, stream>>>(pc, px, py, xn4, xn1, winner);
    fold_k<<<1, 128, 0, stream>>>(norm_g, norm_b, norm_m, norm_v,
                                  w2a, bn2a_g, bn2a_b, bn2a_m, bn2a_v,
                                  bn2b_g, bn2b_b, bn2b_m, bn2b_v, w2b,
                                  conv1_w, conv1_b, final_w, final_b,
                                  w2af8, b2, w2bB, fwallB);
    cnt_k<<<256, 256, 0, stream>>>(winner, blockcnt);
    scan_k<<<1, 256, 0, stream>>>(blockcnt, blockoff, count);
    fill_k<<<256, 256, 0, stream>>>(winner, blockoff, ids);
    pad_k<<<256, 256, 0, stream>>>(ids, count);
    main_k<<<4096, 256, 0, stream>>>(ids, count, neighbors, xn4, xn1, px, py,
                                     b2, w2af8, w2bB, fwallB, out);
}

// Round 6
// 103.264 us; speedup vs baseline: 2.3089x; 1.2904x over previous
//
#include <hip/hip_runtime.h>

#define NPTS 65536
#define WW 1024
#define HWCELLS 65536
#define EPSF 1e-5f
#define QPTS 16

typedef __attribute__((ext_vector_type(8))) short short8;
typedef __attribute__((ext_vector_type(4))) float f32x4;

// tanh-form gelu via exp2+rcp: max |err| vs exact erf-gelu ~3e-4 (below bf16 rounding of g)
__device__ __forceinline__ float gelu_f(float x) {
    float x2 = x * x;
    float q  = fmaf(x2, -0.1029432f, -2.3022160f);   // -(2*0.7978845*[1, 0.044715])*log2(e)
    float e  = __builtin_amdgcn_exp2f(x * q);
    float r  = __builtin_amdgcn_rcpf(1.0f + e);
    return x * r;
}
__device__ __forceinline__ unsigned f2bf_rne(float x) {
    unsigned u = __float_as_uint(x);
    return (u + 0x7fffu + ((u >> 16) & 1u)) >> 16;
}
// HW packed f32x2 -> bf16x2 (RNE on gfx950)
__device__ __forceinline__ unsigned cvtpk(float lo, float hi) {
    unsigned r;
    asm("v_cvt_pk_bf16_f32 %0, %1, %2" : "=v"(r) : "v"(lo), "v"(hi));
    return r;
}

// -1 fill of out (2M float4) + winner init (first 256 blocks)
__global__ void init_out_k(float4* __restrict__ out4, int* __restrict__ winner) {
    int i = blockIdx.x * 256 + threadIdx.x;
    out4[i] = make_float4(-1.f, -1.f, -1.f, -1.f);
    if (i < HWCELLS) winner[i] = -1;
}

// repack pc -> xn4 (c0..c3) + xn1 (c4); winner atomicMax
__global__ void prep_k(const float* __restrict__ pc, const int* __restrict__ px,
                       const int* __restrict__ py,
                       float4* __restrict__ xn4, float* __restrict__ xn1,
                       int* __restrict__ winner) {
    int i = blockIdx.x * blockDim.x + threadIdx.x;
    if (i >= NPTS) return;
    const float* p = &pc[(size_t)i * 5];
    xn4[i] = make_float4(p[0], p[1], p[2], p[3]);
    xn1[i] = p[4];
    int cell = py[i] * WW + px[i];
    atomicMax(&winner[cell], i);
}

__global__ void cnt_k(const int* __restrict__ winner, int* __restrict__ blockcnt) {
    int cell = blockIdx.x * 256 + threadIdx.x;
    bool occ = winner[cell] >= 0;
    unsigned long long m = __ballot(occ);
    __shared__ int wcnt[4];
    int lane = threadIdx.x & 63, wv = threadIdx.x >> 6;
    if (lane == 0) wcnt[wv] = __popcll(m);
    __syncthreads();
    if (threadIdx.x == 0)
        blockcnt[blockIdx.x] = wcnt[0] + wcnt[1] + wcnt[2] + wcnt[3];
}

__global__ void scan_k(const int* __restrict__ blockcnt, int* __restrict__ blockoff,
                       int* __restrict__ count) {
    __shared__ int s[256];
    int t = threadIdx.x;
    int orig = blockcnt[t];
    s[t] = orig;
    __syncthreads();
    for (int off = 1; off < 256; off <<= 1) {
        int v = (t >= off) ? s[t - off] : 0;
        __syncthreads();
        s[t] += v;
        __syncthreads();
    }
    blockoff[t] = s[t] - orig;
    if (t == 255) *count = s[255];
}

// cell-ordered compaction
__global__ void fill_k(const int* __restrict__ winner, const int* __restrict__ blockoff,
                       int* __restrict__ ids) {
    int cell = blockIdx.x * 256 + threadIdx.x;
    int win = winner[cell];
    bool occ = win >= 0;
    unsigned long long m = __ballot(occ);
    __shared__ int wcnt[4];
    int lane = threadIdx.x & 63, wv = threadIdx.x >> 6;
    if (lane == 0) wcnt[wv] = __popcll(m);
    __syncthreads();
    int woff = blockoff[blockIdx.x];
    for (int i = 0; i < wv; ++i) woff += wcnt[i];
    if (occ) {
        int lrank = __popcll(m & ((1ull << lane) - 1));
        ids[woff + lrank] = win;
    }
}

// pad just the tail of the last partial block (<=16 entries)
__global__ void pad_k(int* __restrict__ ids, const int* __restrict__ count) {
    int c = *count;
    int i = c + threadIdx.x;
    if (threadIdx.x < 16 && i < NPTS) ids[i] = ids[0];
}

// fold BN affines into: w2aB8 bf16[128][8] (cols 0..4 = W2A' raw-pc basis, col5 = bias),
// w2bB bf16[128][128], fwallB bf16[128][160]
__global__ void fold_k(const float* __restrict__ ng, const float* __restrict__ nbta,
                       const float* __restrict__ nm, const float* __restrict__ nv,
                       const float* __restrict__ w2a,
                       const float* __restrict__ g2a, const float* __restrict__ b2a,
                       const float* __restrict__ m2a, const float* __restrict__ v2a,
                       const float* __restrict__ g2b, const float* __restrict__ b2b,
                       const float* __restrict__ m2b, const float* __restrict__ v2b,
                       const float* __restrict__ w2b,
                       const float* __restrict__ c1w, const float* __restrict__ c1b,
                       const float* __restrict__ fw, const float* __restrict__ fbias,
                       unsigned short* __restrict__ w2aB8,
                       unsigned short* __restrict__ w2bB,
                       unsigned short* __restrict__ fwallB) {
    __shared__ float c1wS[640];
    __shared__ float c1adjS[128];
    int d = threadIdx.x;  // 0..127

    float s_n[5], t_n[5];
#pragma unroll
    for (int c = 0; c < 5; ++c) {
        s_n[c] = ng[c] * rsqrtf(nv[c] + EPSF);
        t_n[c] = nbta[c] - nm[c] * s_n[c];
    }
    for (int j = d; j < 640; j += 128) c1wS[j] = c1w[j];
    __syncthreads();
    {
        float a = c1b[d];
#pragma unroll
        for (int c = 0; c < 5; ++c) a += c1wS[d * 5 + c] * t_n[c];
        c1adjS[d] = a;
    }
    __syncthreads();

    float s2b = g2b[d] * rsqrtf(v2b[d] + EPSF);
    float t2b = b2b[d] - m2b[d] * s2b;
    float acc = 0.f;
#pragma unroll
    for (int c = 0; c < 5; ++c) {
        float s2a = g2a[c] * rsqrtf(v2a[c] + EPSF);
        float t2a = b2a[c] - m2a[c] * s2a;
        float wv = w2a[d * 5 + c];
        w2aB8[d * 8 + c] = (unsigned short)f2bf_rne(s2b * wv * s2a * s_n[c]);
        acc += s2b * wv * t2a;
    }
    w2aB8[d * 8 + 5] = (unsigned short)f2bf_rne(acc + t2b);  // bias via dx[5]=1
    w2aB8[d * 8 + 6] = 0; w2aB8[d * 8 + 7] = 0;

#pragma unroll 8
    for (int i4 = 0; i4 < 32; ++i4) {
        float4 v = *(const float4*)&w2b[d * 128 + i4 * 4];
        unsigned short* dst = &w2bB[d * 128 + i4 * 4];
        dst[0] = (unsigned short)f2bf_rne(v.x);
        dst[1] = (unsigned short)f2bf_rne(v.y);
        dst[2] = (unsigned short)f2bf_rne(v.z);
        dst[3] = (unsigned short)f2bf_rne(v.w);
    }

    float f1[5] = {0.f, 0.f, 0.f, 0.f, 0.f};
    float fbv = fbias[d];
#pragma unroll 8
    for (int d4 = 0; d4 < 32; ++d4) {
        float4 fv = *(const float4*)&fw[d * 256 + d4 * 4];
        float4 fn = *(const float4*)&fw[d * 256 + 128 + d4 * 4];
        unsigned short* dst = &fwallB[d * 160 + d4 * 4];
        dst[0] = (unsigned short)f2bf_rne(fn.x);
        dst[1] = (unsigned short)f2bf_rne(fn.y);
        dst[2] = (unsigned short)f2bf_rne(fn.z);
        dst[3] = (unsigned short)f2bf_rne(fn.w);
        int dd = d4 * 4;
        fbv += fv.x * c1adjS[dd] + fv.y * c1adjS[dd+1] + fv.z * c1adjS[dd+2] + fv.w * c1adjS[dd+3];
#pragma unroll
        for (int c = 0; c < 5; ++c)
            f1[c] += fv.x * c1wS[dd*5 + c] + fv.y * c1wS[(dd+1)*5 + c]
                   + fv.z * c1wS[(dd+2)*5 + c] + fv.w * c1wS[(dd+3)*5 + c];
    }
#pragma unroll
    for (int c = 0; c < 5; ++c)
        fwallB[d * 160 + 128 + c] = (unsigned short)f2bf_rne(f1[c] * s_n[c]);
    fwallB[d * 160 + 133] = (unsigned short)f2bf_rne(fbv);
    for (int j = 134; j < 160; ++j) fwallB[d * 160 + j] = 0;
}

// fused MFMA main: 16 pts/block, 256 thr (4 waves); no global traffic in k-loop
__launch_bounds__(256, 6)
__global__ void main_k(const int* __restrict__ ids, const int* __restrict__ countp,
                       const int* __restrict__ nbrs,
                       const float4* __restrict__ xn4, const float* __restrict__ xn1,
                       const int* __restrict__ px, const int* __restrict__ py,
                       const unsigned short* __restrict__ w2aB8,
                       const unsigned short* __restrict__ w2bB,
                       const unsigned short* __restrict__ fwallB,
                       float* __restrict__ outp) {
    const int n0 = blockIdx.x * QPTS;
    if (n0 >= *countp) return;

    __shared__ char           lds[8192];          // G dbuf (2x4096); M (5120) overlays
    __shared__ unsigned short dxS[15 * 16 * 8];   // bf16 [kk][pt][8]: dx0..4,1.0,0,0
    __shared__ int   idS[QPTS];
    __shared__ int   nbS[QPTS * 16];
    __shared__ float xnS[QPTS][5];
    __shared__ int   cellS[QPTS];

    const int t = threadIdx.x;
    const int w = t >> 6;
    const int l = t & 63;
    const int l15 = l & 15;
    const int lg  = l >> 4;

    if (t < QPTS) idS[t] = ids[n0 + t];
    __syncthreads();

    nbS[t] = nbrs[idS[t >> 4] * 16 + (t & 15)];
    if (t < QPTS) {
        int id = idS[t];
        float4 a = xn4[id];
        xnS[t][0] = a.x; xnS[t][1] = a.y; xnS[t][2] = a.z; xnS[t][3] = a.w;
        xnS[t][4] = xn1[id];
        cellS[t] = py[id] * WW + px[id];
    }

    // A1: folded W2A'|bias rows (only lg==0 lanes carry k=0..7; rest zero)
    short8 a1[2] = { {0,0,0,0,0,0,0,0}, {0,0,0,0,0,0,0,0} };
    if (lg == 0) {
        a1[0] = *(const short8*)(w2aB8 + (w * 32 + l15) * 8);
        a1[1] = *(const short8*)(w2aB8 + (w * 32 + 16 + l15) * 8);
    }
    // A2: w2b rows [w*32, w*32+32), K=128
    short8 a2[2][4];
#pragma unroll
    for (int rt = 0; rt < 2; ++rt)
#pragma unroll
        for (int ks = 0; ks < 4; ++ks)
            a2[rt][ks] = *(const short8*)(w2bB + (w * 32 + rt * 16 + l15) * 128 + ks * 32 + lg * 8);

    __syncthreads();  // nbS + xnS ready

    // build dx tile: one gather per (pt,kk)
    if (t < 240) {
        int pt = t & 15, kk = t >> 4;
        int nb = nbS[pt * 16 + kk + 1];
        float4 a = xn4[nb];
        float  e = xn1[nb];
        float d0 = a.x - xnS[pt][0];
        float d1 = a.y - xnS[pt][1];
        float d2 = a.z - xnS[pt][2];
        float d3 = a.w - xnS[pt][3];
        float d4 = e   - xnS[pt][4];
        uint4 v;
        v.x = cvtpk(d0, d1);
        v.y = cvtpk(d2, d3);
        v.z = cvtpk(d4, 1.0f);
        v.w = 0u;
        *(uint4*)&dxS[(kk * 16 + pt) * 8] = v;
    }
    __syncthreads();  // dxS ready

    const f32x4 zero4 = {0.f, 0.f, 0.f, 0.f};
    f32x4 mmax[2];
#pragma unroll
    for (int rt = 0; rt < 2; ++rt)
#pragma unroll
        for (int j = 0; j < 4; ++j) mmax[rt][j] = -1e30f;

    for (int kk = 0; kk < 15; ++kk) {
        // MFMA1: s[din][pt] = W2A'|b2 @ [dx;1]  (broadcast LDS read; lg!=0 rows of A are 0)
        short8 dxf = *(const short8*)&dxS[(kk * 16 + l15) * 8];
        char* Gb = lds + (kk & 1) * 4096;
#pragma unroll
        for (int rt = 0; rt < 2; ++rt) {
            f32x4 s = __builtin_amdgcn_mfma_f32_16x16x32_bf16(a1[rt], dxf, zero4, 0, 0, 0);
            uint2 pr;
            pr.x = cvtpk(gelu_f(s[0]), gelu_f(s[1]));
            pr.y = cvtpk(gelu_f(s[2]), gelu_f(s[3]));
            int din0 = w * 32 + rt * 16 + lg * 4;
            *(uint2*)(Gb + l15 * 256 + ((din0 * 2) ^ (l15 << 4))) = pr;
        }
        __syncthreads();
        // MFMA2: u = w2b @ G; running max
        f32x4 acc[2];
#pragma unroll
        for (int ks = 0; ks < 4; ++ks) {
            int kb = (ks * 32 + lg * 8) * 2;
            short8 bfrag = *(const short8*)(Gb + l15 * 256 + (kb ^ (l15 << 4)));
#pragma unroll
            for (int rt = 0; rt < 2; ++rt)
                acc[rt] = __builtin_amdgcn_mfma_f32_16x16x32_bf16(
                    a2[rt][ks], bfrag, ks == 0 ? zero4 : acc[rt], 0, 0, 0);
        }
#pragma unroll
        for (int rt = 0; rt < 2; ++rt)
#pragma unroll
            for (int j = 0; j < 4; ++j)
                mmax[rt][j] = fmaxf(mmax[rt][j], acc[rt][j]);
    }

    __syncthreads();  // all MFMA2 reads done before M overlay

    // running max -> M [pt][k] bf16 (k<128 swizzled) + xn|1 tail (k=128..)
    {
        char* Mb = lds;
        int sw = l15 << 4;
#pragma unroll
        for (int rt = 0; rt < 2; ++rt) {
            int dout = w * 32 + rt * 16 + lg * 4;
            unsigned lo = cvtpk(mmax[rt][0], mmax[rt][1]);
            unsigned hi = cvtpk(mmax[rt][2], mmax[rt][3]);
            *(unsigned*)(Mb + l15 * 320 + ((dout * 2) ^ sw)) = lo;
            *(unsigned*)(Mb + l15 * 320 + (((dout + 2) * 2) ^ sw)) = hi;
        }
        if (t < QPTS) {
            uint4 a;
            a.x = cvtpk(xnS[t][0], xnS[t][1]);
            a.y = cvtpk(xnS[t][2], xnS[t][3]);
            a.z = cvtpk(xnS[t][4], 1.0f);
            a.w = 0u;
            uint4 z; z.x = 0u; z.y = 0u; z.z = 0u; z.w = 0u;
            *(uint4*)(Mb + t * 320 + 256) = a;
            *(uint4*)(Mb + t * 320 + 272) = z;
            *(uint4*)(Mb + t * 320 + 288) = z;
            *(uint4*)(Mb + t * 320 + 304) = z;
        }
    }
    __syncthreads();

    // final GEMM: feats[e][pt] = fwallB(128x160) @ M(160xQPTS)
    f32x4 facc[2];
    const char* Mr = lds;
#pragma unroll
    for (int ks = 0; ks < 5; ++ks) {
        short8 af[2];
#pragma unroll
        for (int rt = 0; rt < 2; ++rt)
            af[rt] = *(const short8*)(fwallB + (w * 32 + rt * 16 + l15) * 160 + ks * 32 + lg * 8);
        int kb = (ks * 32 + lg * 8) * 2;
        int kbs = (kb < 256) ? (kb ^ (l15 << 4)) : kb;
        short8 bfr = *(const short8*)(Mr + l15 * 320 + kbs);
#pragma unroll
        for (int rt = 0; rt < 2; ++rt)
            facc[rt] = __builtin_amdgcn_mfma_f32_16x16x32_bf16(
                af[rt], bfr, ks == 0 ? zero4 : facc[rt], 0, 0, 0);
    }

    // direct scatter: cells ascending within block -> near-coalesced lines
    const int cell = cellS[l15];
#pragma unroll
    for (int rt = 0; rt < 2; ++rt) {
        int e0 = w * 32 + rt * 16 + lg * 4;
#pragma unroll
        for (int j = 0; j < 4; ++j)
            outp[(size_t)(e0 + j) * HWCELLS + cell] = facc[rt][j];
    }
}

extern "C" void kernel_launch(void* const* d_in, const int* in_sizes, int n_in,
                              void* d_out, int out_size, void* d_ws, size_t ws_size,
                              hipStream_t stream) {
    const float* pc        = (const float*)d_in[0];
    const int*   neighbors = (const int*)d_in[1];
    const int*   px        = (const int*)d_in[2];
    const int*   py        = (const int*)d_in[3];
    const float* norm_g    = (const float*)d_in[4];
    const float* norm_b    = (const float*)d_in[5];
    const float* norm_m    = (const float*)d_in[6];
    const float* norm_v    = (const float*)d_in[7];
    const float* conv1_w   = (const float*)d_in[8];
    const float* conv1_b   = (const float*)d_in[9];
    const float* bn2a_g    = (const float*)d_in[10];
    const float* bn2a_b    = (const float*)d_in[11];
    const float* bn2a_m    = (const float*)d_in[12];
    const float* bn2a_v    = (const float*)d_in[13];
    const float* w2a       = (const float*)d_in[14];
    const float* bn2b_g    = (const float*)d_in[15];
    const float* bn2b_b    = (const float*)d_in[16];
    const float* bn2b_m    = (const float*)d_in[17];
    const float* bn2b_v    = (const float*)d_in[18];
    const float* w2b       = (const float*)d_in[19];
    const float* final_w   = (const float*)d_in[20];
    const float* final_b   = (const float*)d_in[21];
    float* out = (float*)d_out;

    char* ws = (char*)d_ws;
    float4*         xn4      = (float4*)(ws);                     // 1,048,576 B
    float*          xn1      = (float*)(ws + 1048576);            //   262,144 B
    int*            winner   = (int*)(ws + 1310720);              //   262,144 B
    int*            ids      = (int*)(ws + 1572864);              //   262,144 B
    int*            count    = (int*)(ws + 1835008);              //       256 B
    int*            blockcnt = (int*)(ws + 1835264);              //     1,024 B
    int*            blockoff = (int*)(ws + 1836288);              //     1,024 B
    unsigned short* w2aB8    = (unsigned short*)(ws + 1837312);   //     2,048 B
    unsigned short* w2bB     = (unsigned short*)(ws + 1839360);   //    32,768 B
    unsigned short* fwallB   = (unsigned short*)(ws + 1872128);   //    40,960 B

    init_out_k<<<8192, 256, 0, stream>>>((float4*)out, winner);
    prep_k<<<256, 256, 0, stream>>>(pc, px, py, xn4, xn1, winner);
    fold_k<<<1, 128, 0, stream>>>(norm_g, norm_b, norm_m, norm_v,
                                  w2a, bn2a_g, bn2a_b, bn2a_m, bn2a_v,
                                  bn2b_g, bn2b_b, bn2b_m, bn2b_v, w2b,
                                  conv1_w, conv1_b, final_w, final_b,
                                  w2aB8, w2bB, fwallB);
    cnt_k<<<256, 256, 0, stream>>>(winner, blockcnt);
    scan_k<<<1, 256, 0, stream>>>(blockcnt, blockoff, count);
    fill_k<<<256, 256, 0, stream>>>(winner, blockoff, ids);
    pad_k<<<1, 64, 0, stream>>>(ids, count);
    main_k<<<4096, 256, 0, stream>>>(ids, count, neighbors, xn4, xn1, px, py,
                                     w2aB8, w2bB, fwallB, out);
}